// Round 17
// baseline (35.343 us; speedup 1.0000x reference)
//
#include <hip/hip_runtime.h>
#include <hip/hip_bf16.h>
#include <hip/hip_fp16.h>

// Siren fused, 32x32x16 fp16 MFMA, zero-LDS, triple sigma-cancellation.
// R17: PIPE BALANCING. Calibrated model: VALU ~2.6 cyc/inst, v_sin ~21
// cyc/wave64 -> R16 was trans-bound (72 trans = ~74% of wave time). Stream A's
// 32 activation sines move to the deg-7 minimax poly on the FMA pipe (R11's
// poly regression was confounded by the slow software bf16 pack, since fixed);
// stream B and the 8 enc seeds stay on v_sin. trans 72->40, VALU +224 insts:
// both pipes ~balanced at ~1000 cyc/wave.

typedef _Float16 half8 __attribute__((ext_vector_type(8)));
typedef __fp16 fp16x2 __attribute__((ext_vector_type(2)));
typedef float f32x16 __attribute__((ext_vector_type(16)));

#define THREADS 256
#define INV2PI 0.15915494309189535f

// single-inst packed f32->fp16 (RTZ)
__device__ __forceinline__ unsigned packh(float lo, float hi) {
    union { fp16x2 h; unsigned u; } v;
    v.h = __builtin_amdgcn_cvt_pkrtz(lo, hi);
    return v.u;
}

__device__ __forceinline__ unsigned packh_rne(float lo, float hi) {
    union { _Float16 h[2]; unsigned u; } v;
    v.h[0] = (_Float16)lo;
    v.h[1] = (_Float16)hi;
    return v.u;
}

// sin(2*pi*r), r in revolutions, via deg-7 odd minimax on the FMA pipe.
// Chebyshev-Bessel coeffs; |err| <= 2*J9(pi) ~ 2.6e-4 (<< fp16 quant).
__device__ __forceinline__ float sin2pi_poly(float r) {
    float x = r - __builtin_rintf(r);       // [-0.5, 0.5]
    float y = x * x;
    float p = fmaf(y, -56.033280f, 77.910016f);
    p = fmaf(y, p, -41.090432f);
    p = fmaf(y, p, 6.2784272f);
    return x * p;
}

// enc chain: 12 sin + 12 cos of pi*2^j*xd via 2 seeds + 10 double-angle steps.
__device__ __forceinline__ void enc_chain(float xd, float sv[12], float cv[12]) {
    sv[0] = __builtin_amdgcn_sinf(xd * 0.5f);
    cv[0] = __builtin_amdgcn_cosf(xd * 0.5f);
#pragma unroll
    for (int j = 1; j < 6; ++j) {
        float t = sv[j - 1] + sv[j - 1];
        sv[j] = t * cv[j - 1];
        cv[j] = fmaf(-t, sv[j - 1], 1.0f);
    }
    sv[6] = __builtin_amdgcn_sinf(xd * 32.0f);
    cv[6] = __builtin_amdgcn_cosf(xd * 32.0f);
#pragma unroll
    for (int j = 7; j < 12; ++j) {
        float t = sv[j - 1] + sv[j - 1];
        sv[j] = t * cv[j - 1];
        cv[j] = fmaf(-t, sv[j - 1], 1.0f);
    }
}

// ---- bake per-lane A fragments, fp16, 32x32x16 (layout as R16) ----
__global__ void build_frags(const float* __restrict__ W0,
                            const float* __restrict__ W1,
                            const float* __restrict__ W2,
                            uint4* __restrict__ ws) {
    int l = threadIdx.x;
    if (l >= 64) return;
    int h = l >> 5, c = l & 31;

#pragma unroll
    for (int t = 0; t < 3; ++t) {
        float ev[8];
#pragma unroll
        for (int e = 0; e < 8; ++e) ev[e] = W0[(h * 24 + 8 * t + e) * 32 + c] * INV2PI;
        ws[t * 64 + l] = make_uint4(packh_rne(ev[0], ev[1]), packh_rne(ev[2], ev[3]),
                                    packh_rne(ev[4], ev[5]), packh_rne(ev[6], ev[7]));
    }
#pragma unroll
    for (int t = 0; t < 2; ++t) {
        float ev[8];
#pragma unroll
        for (int e = 0; e < 8; ++e) {
            int k = (e & 3) + 8 * (e >> 2) + 4 * h + 16 * t;
            ev[e] = W1[k * 32 + c] * INV2PI;
        }
        ws[(3 + t) * 64 + l] = make_uint4(packh_rne(ev[0], ev[1]), packh_rne(ev[2], ev[3]),
                                          packh_rne(ev[4], ev[5]), packh_rne(ev[6], ev[7]));
    }
    // dot fragments: W2 in row 0 (stream 0) / row 4 (stream 1)
#pragma unroll
    for (int s = 0; s < 2; ++s)
#pragma unroll
        for (int t = 0; t < 2; ++t) {
            float ev[8];
#pragma unroll
            for (int e = 0; e < 8; ++e) {
                int k = (e & 3) + 8 * (e >> 2) + 4 * h + 16 * t;
                ev[e] = (c == 4 * s) ? W2[k] : 0.0f;
            }
            ws[(5 + 2 * s + t) * 64 + l] = make_uint4(packh_rne(ev[0], ev[1]), packh_rne(ev[2], ev[3]),
                                                      packh_rne(ev[4], ev[5]), packh_rne(ev[6], ev[7]));
        }
}

__global__ __launch_bounds__(THREADS, 4) void siren_mfma_kernel(
    const float* __restrict__ xf,     // [N][2] flat
    const uint4* __restrict__ wf,
    float* __restrict__ out,
    int n)
{
    const int lane = threadIdx.x & 63;
    const int wid = threadIdx.x >> 6;
    const int q = lane & 31, h = lane >> 5;
    const int p0 = blockIdx.x * THREADS + wid * 64;
    if (p0 >= n) return;

    const float xd0 = xf[(p0 + q) * 2 + h];
    const float xd1 = xf[(p0 + 32 + q) * 2 + h];

    union U { uint4 u; half8 v; };
    half8 a0[3], a1[2], d0[2], d1[2];
#pragma unroll
    for (int t = 0; t < 3; ++t) { U tt; tt.u = wf[t * 64 + lane]; a0[t] = tt.v; }
#pragma unroll
    for (int t = 0; t < 2; ++t) { U tt; tt.u = wf[(3 + t) * 64 + lane]; a1[t] = tt.v; }
#pragma unroll
    for (int t = 0; t < 2; ++t) { U tt; tt.u = wf[(5 + t) * 64 + lane]; d0[t] = tt.v; }
#pragma unroll
    for (int t = 0; t < 2; ++t) { U tt; tt.u = wf[(7 + t) * 64 + lane]; d1[t] = tt.v; }

    f32x16 zacc;
#pragma unroll
    for (int i = 0; i < 16; ++i) zacc[i] = 0.0f;

    union F { unsigned u[4]; half8 v; };

    // ===== stream 0: enc + L0 =====
    F bf00, bf01, bf02;
    {
        float sv[12], cv[12];
        enc_chain(xd0, sv, cv);
        bf00.u[0] = packh(sv[0], sv[1]);  bf00.u[1] = packh(sv[2], sv[3]);
        bf00.u[2] = packh(sv[4], sv[5]);  bf00.u[3] = packh(sv[6], sv[7]);
        bf01.u[0] = packh(sv[8], sv[9]);  bf01.u[1] = packh(sv[10], sv[11]);
        bf01.u[2] = packh(cv[0], cv[1]);  bf01.u[3] = packh(cv[2], cv[3]);
        bf02.u[0] = packh(cv[4], cv[5]);  bf02.u[1] = packh(cv[6], cv[7]);
        bf02.u[2] = packh(cv[8], cv[9]);  bf02.u[3] = packh(cv[10], cv[11]);
    }
    f32x16 accA;
    accA = __builtin_amdgcn_mfma_f32_32x32x16_f16(a0[0], bf00.v, zacc, 0, 0, 0);
    accA = __builtin_amdgcn_mfma_f32_32x32x16_f16(a0[1], bf01.v, accA, 0, 0, 0);
    accA = __builtin_amdgcn_mfma_f32_32x32x16_f16(a0[2], bf02.v, accA, 0, 0, 0);

    // ===== stream 1: enc + L0 =====
    F bf10, bf11, bf12;
    {
        float sv[12], cv[12];
        enc_chain(xd1, sv, cv);
        bf10.u[0] = packh(sv[0], sv[1]);  bf10.u[1] = packh(sv[2], sv[3]);
        bf10.u[2] = packh(sv[4], sv[5]);  bf10.u[3] = packh(sv[6], sv[7]);
        bf11.u[0] = packh(sv[8], sv[9]);  bf11.u[1] = packh(sv[10], sv[11]);
        bf11.u[2] = packh(cv[0], cv[1]);  bf11.u[3] = packh(cv[2], cv[3]);
        bf12.u[0] = packh(cv[4], cv[5]);  bf12.u[1] = packh(cv[6], cv[7]);
        bf12.u[2] = packh(cv[8], cv[9]);  bf12.u[3] = packh(cv[10], cv[11]);
    }
    f32x16 accB;
    accB = __builtin_amdgcn_mfma_f32_32x32x16_f16(a0[0], bf10.v, zacc, 0, 0, 0);
    accB = __builtin_amdgcn_mfma_f32_32x32x16_f16(a0[1], bf11.v, accB, 0, 0, 0);
    accB = __builtin_amdgcn_mfma_f32_32x32x16_f16(a0[2], bf12.v, accB, 0, 0, 0);

    // ===== act0 (POLY, FMA pipe) + L1(0) =====
    F b1a0, b1b0;
#pragma unroll
    for (int i = 0; i < 4; ++i)
        b1a0.u[i] = packh(sin2pi_poly(accA[2 * i]), sin2pi_poly(accA[2 * i + 1]));
#pragma unroll
    for (int i = 0; i < 4; ++i)
        b1b0.u[i] = packh(sin2pi_poly(accA[8 + 2 * i]), sin2pi_poly(accA[8 + 2 * i + 1]));
    f32x16 acc1A;
    acc1A = __builtin_amdgcn_mfma_f32_32x32x16_f16(a1[0], b1a0.v, zacc, 0, 0, 0);
    acc1A = __builtin_amdgcn_mfma_f32_32x32x16_f16(a1[1], b1b0.v, acc1A, 0, 0, 0);

    // ===== act1 (v_sin, trans pipe) + L1(1) =====
    F b1a1, b1b1;
#pragma unroll
    for (int i = 0; i < 4; ++i)
        b1a1.u[i] = packh(__builtin_amdgcn_sinf(accB[2 * i]),
                          __builtin_amdgcn_sinf(accB[2 * i + 1]));
#pragma unroll
    for (int i = 0; i < 4; ++i)
        b1b1.u[i] = packh(__builtin_amdgcn_sinf(accB[8 + 2 * i]),
                          __builtin_amdgcn_sinf(accB[8 + 2 * i + 1]));
    f32x16 acc1B;
    acc1B = __builtin_amdgcn_mfma_f32_32x32x16_f16(a1[0], b1a1.v, zacc, 0, 0, 0);
    acc1B = __builtin_amdgcn_mfma_f32_32x32x16_f16(a1[1], b1b1.v, acc1B, 0, 0, 0);

    // ===== act2-A (POLY) + dot-MFMA A =====
    F b2a0, b2b0;
#pragma unroll
    for (int i = 0; i < 4; ++i)
        b2a0.u[i] = packh(sin2pi_poly(acc1A[2 * i]), sin2pi_poly(acc1A[2 * i + 1]));
#pragma unroll
    for (int i = 0; i < 4; ++i)
        b2b0.u[i] = packh(sin2pi_poly(acc1A[8 + 2 * i]), sin2pi_poly(acc1A[8 + 2 * i + 1]));
    f32x16 accDA;
    accDA = __builtin_amdgcn_mfma_f32_32x32x16_f16(d0[0], b2a0.v, zacc, 0, 0, 0);
    accDA = __builtin_amdgcn_mfma_f32_32x32x16_f16(d0[1], b2b0.v, accDA, 0, 0, 0);

    // ===== act2-B (v_sin) + dot-MFMA B =====
    F b2a1, b2b1;
#pragma unroll
    for (int i = 0; i < 4; ++i)
        b2a1.u[i] = packh(__builtin_amdgcn_sinf(acc1B[2 * i]),
                          __builtin_amdgcn_sinf(acc1B[2 * i + 1]));
#pragma unroll
    for (int i = 0; i < 4; ++i)
        b2b1.u[i] = packh(__builtin_amdgcn_sinf(acc1B[8 + 2 * i]),
                          __builtin_amdgcn_sinf(acc1B[8 + 2 * i + 1]));
    f32x16 accDB;
    accDB = __builtin_amdgcn_mfma_f32_32x32x16_f16(d1[0], b2a1.v, zacc, 0, 0, 0);
    accDB = __builtin_amdgcn_mfma_f32_32x32x16_f16(d1[1], b2b1.v, accDB, 0, 0, 0);

    // ===== store: reg 0 of lane (h,q) = C[row 4h][q] = dot of point 32h+q =====
    out[p0 + 32 * h + q] = h ? accDB[0] : accDA[0];
}

extern "C" void kernel_launch(void* const* d_in, const int* in_sizes, int n_in,
                              void* d_out, int out_size, void* d_ws, size_t ws_size,
                              hipStream_t stream) {
    const float* xf = (const float*)d_in[0];
    const float* W0 = (const float*)d_in[1];
    const float* W1 = (const float*)d_in[2];
    const float* W2 = (const float*)d_in[3];
    float* out = (float*)d_out;
    uint4* ws = (uint4*)d_ws;

    const int n = in_sizes[0] / 2;
    build_frags<<<1, 64, 0, stream>>>(W0, W1, W2, ws);
    const int blocks = (n + THREADS - 1) / THREADS;
    siren_mfma_kernel<<<blocks, THREADS, 0, stream>>>(xf, ws, out, n);
}

// Round 18
// 30.735 us; speedup vs baseline: 1.1499x; 1.1499x over previous
//
#include <hip/hip_runtime.h>
#include <hip/hip_bf16.h>
#include <hip/hip_fp16.h>

// Siren fused, 32x32x16 fp16 MFMA, zero-LDS, triple sigma-cancellation.
// R18: PERSISTENT WAVES. R17's clean +224-VALU = +5us delta proved VALU issue
// is fully serialized while trans is ~free -> R16 was latency/fixed-cost
// bound: every 64-pt wave re-paid 9 weight-frag loads + x-load latency + ramp.
// Now grid = 1024 blocks (exactly the 4-waves/EU resident capacity); each wave
// loops 8 tiles, weights load once/wave, next tile's x prefetched under the
// current tile's compute. Dot MFMAs merged into ONE accumulator (d0 -> C row 0,
// d1 -> C row 4 = reg0 of h=0/h=1 lanes) -> -16 VGPR and no final select.
// All activations back on v_sin (R17 poly reverted).

typedef _Float16 half8 __attribute__((ext_vector_type(8)));
typedef __fp16 fp16x2 __attribute__((ext_vector_type(2)));
typedef float f32x16 __attribute__((ext_vector_type(16)));

#define THREADS 256
#define INV2PI 0.15915494309189535f

__device__ __forceinline__ unsigned packh(float lo, float hi) {
    union { fp16x2 h; unsigned u; } v;
    v.h = __builtin_amdgcn_cvt_pkrtz(lo, hi);
    return v.u;
}

__device__ __forceinline__ unsigned packh_rne(float lo, float hi) {
    union { _Float16 h[2]; unsigned u; } v;
    v.h[0] = (_Float16)lo;
    v.h[1] = (_Float16)hi;
    return v.u;
}

// enc chain: 12 sin + 12 cos of pi*2^j*xd via 2 seeds + 10 double-angle steps.
__device__ __forceinline__ void enc_chain(float xd, float sv[12], float cv[12]) {
    sv[0] = __builtin_amdgcn_sinf(xd * 0.5f);
    cv[0] = __builtin_amdgcn_cosf(xd * 0.5f);
#pragma unroll
    for (int j = 1; j < 6; ++j) {
        float t = sv[j - 1] + sv[j - 1];
        sv[j] = t * cv[j - 1];
        cv[j] = fmaf(-t, sv[j - 1], 1.0f);
    }
    sv[6] = __builtin_amdgcn_sinf(xd * 32.0f);
    cv[6] = __builtin_amdgcn_cosf(xd * 32.0f);
#pragma unroll
    for (int j = 7; j < 12; ++j) {
        float t = sv[j - 1] + sv[j - 1];
        sv[j] = t * cv[j - 1];
        cv[j] = fmaf(-t, sv[j - 1], 1.0f);
    }
}

// ---- bake per-lane A fragments, fp16, 32x32x16 (layout as R16) ----
__global__ void build_frags(const float* __restrict__ W0,
                            const float* __restrict__ W1,
                            const float* __restrict__ W2,
                            uint4* __restrict__ ws) {
    int l = threadIdx.x;
    if (l >= 64) return;
    int h = l >> 5, c = l & 31;

#pragma unroll
    for (int t = 0; t < 3; ++t) {
        float ev[8];
#pragma unroll
        for (int e = 0; e < 8; ++e) ev[e] = W0[(h * 24 + 8 * t + e) * 32 + c] * INV2PI;
        ws[t * 64 + l] = make_uint4(packh_rne(ev[0], ev[1]), packh_rne(ev[2], ev[3]),
                                    packh_rne(ev[4], ev[5]), packh_rne(ev[6], ev[7]));
    }
#pragma unroll
    for (int t = 0; t < 2; ++t) {
        float ev[8];
#pragma unroll
        for (int e = 0; e < 8; ++e) {
            int k = (e & 3) + 8 * (e >> 2) + 4 * h + 16 * t;
            ev[e] = W1[k * 32 + c] * INV2PI;
        }
        ws[(3 + t) * 64 + l] = make_uint4(packh_rne(ev[0], ev[1]), packh_rne(ev[2], ev[3]),
                                          packh_rne(ev[4], ev[5]), packh_rne(ev[6], ev[7]));
    }
    // dot fragments: W2 in row 0 (stream 0) / row 4 (stream 1)
#pragma unroll
    for (int s = 0; s < 2; ++s)
#pragma unroll
        for (int t = 0; t < 2; ++t) {
            float ev[8];
#pragma unroll
            for (int e = 0; e < 8; ++e) {
                int k = (e & 3) + 8 * (e >> 2) + 4 * h + 16 * t;
                ev[e] = (c == 4 * s) ? W2[k] : 0.0f;
            }
            ws[(5 + 2 * s + t) * 64 + l] = make_uint4(packh_rne(ev[0], ev[1]), packh_rne(ev[2], ev[3]),
                                                      packh_rne(ev[4], ev[5]), packh_rne(ev[6], ev[7]));
        }
}

#define BLOCKS 1024

__global__ __launch_bounds__(THREADS, 4) void siren_mfma_kernel(
    const float* __restrict__ xf,     // [N][2] flat
    const uint4* __restrict__ wf,
    float* __restrict__ out,
    int n, int chunk)                 // chunk = points per wave (multiple of 64)
{
    const int lane = threadIdx.x & 63;
    const int wid = threadIdx.x >> 6;
    const int q = lane & 31, h = lane >> 5;
    const int wgid = blockIdx.x * 4 + wid;

    int p0 = wgid * chunk;
    if (p0 >= n) return;
    const int pend = min(p0 + chunk, n);

    // ---- weights: loaded ONCE per wave ----
    union U { uint4 u; half8 v; };
    half8 a0[3], a1[2], d0[2], d1[2];
#pragma unroll
    for (int t = 0; t < 3; ++t) { U tt; tt.u = wf[t * 64 + lane]; a0[t] = tt.v; }
#pragma unroll
    for (int t = 0; t < 2; ++t) { U tt; tt.u = wf[(3 + t) * 64 + lane]; a1[t] = tt.v; }
#pragma unroll
    for (int t = 0; t < 2; ++t) { U tt; tt.u = wf[(5 + t) * 64 + lane]; d0[t] = tt.v; }
#pragma unroll
    for (int t = 0; t < 2; ++t) { U tt; tt.u = wf[(7 + t) * 64 + lane]; d1[t] = tt.v; }

    f32x16 zacc;
#pragma unroll
    for (int i = 0; i < 16; ++i) zacc[i] = 0.0f;

    union F { unsigned u[4]; half8 v; };

    // ---- first tile's x in flight ----
    float xa = xf[(p0 + q) * 2 + h];
    float xb = xf[(p0 + 32 + q) * 2 + h];

    for (int p = p0; p < pend; p += 64) {
        // ---- prefetch next tile's x (hides under this tile's compute) ----
        const int pn = (p + 64 < pend) ? (p + 64) : p;
        float na = xf[(pn + q) * 2 + h];
        float nb = xf[(pn + 32 + q) * 2 + h];

        // ===== stream 0: enc + L0 =====
        F bf00, bf01, bf02;
        {
            float sv[12], cv[12];
            enc_chain(xa, sv, cv);
            bf00.u[0] = packh(sv[0], sv[1]);  bf00.u[1] = packh(sv[2], sv[3]);
            bf00.u[2] = packh(sv[4], sv[5]);  bf00.u[3] = packh(sv[6], sv[7]);
            bf01.u[0] = packh(sv[8], sv[9]);  bf01.u[1] = packh(sv[10], sv[11]);
            bf01.u[2] = packh(cv[0], cv[1]);  bf01.u[3] = packh(cv[2], cv[3]);
            bf02.u[0] = packh(cv[4], cv[5]);  bf02.u[1] = packh(cv[6], cv[7]);
            bf02.u[2] = packh(cv[8], cv[9]);  bf02.u[3] = packh(cv[10], cv[11]);
        }
        f32x16 accA;
        accA = __builtin_amdgcn_mfma_f32_32x32x16_f16(a0[0], bf00.v, zacc, 0, 0, 0);
        accA = __builtin_amdgcn_mfma_f32_32x32x16_f16(a0[1], bf01.v, accA, 0, 0, 0);
        accA = __builtin_amdgcn_mfma_f32_32x32x16_f16(a0[2], bf02.v, accA, 0, 0, 0);

        // ===== stream 1: enc + L0 =====
        F bf10, bf11, bf12;
        {
            float sv[12], cv[12];
            enc_chain(xb, sv, cv);
            bf10.u[0] = packh(sv[0], sv[1]);  bf10.u[1] = packh(sv[2], sv[3]);
            bf10.u[2] = packh(sv[4], sv[5]);  bf10.u[3] = packh(sv[6], sv[7]);
            bf11.u[0] = packh(sv[8], sv[9]);  bf11.u[1] = packh(sv[10], sv[11]);
            bf11.u[2] = packh(cv[0], cv[1]);  bf11.u[3] = packh(cv[2], cv[3]);
            bf12.u[0] = packh(cv[4], cv[5]);  bf12.u[1] = packh(cv[6], cv[7]);
            bf12.u[2] = packh(cv[8], cv[9]);  bf12.u[3] = packh(cv[10], cv[11]);
        }
        f32x16 accB;
        accB = __builtin_amdgcn_mfma_f32_32x32x16_f16(a0[0], bf10.v, zacc, 0, 0, 0);
        accB = __builtin_amdgcn_mfma_f32_32x32x16_f16(a0[1], bf11.v, accB, 0, 0, 0);
        accB = __builtin_amdgcn_mfma_f32_32x32x16_f16(a0[2], bf12.v, accB, 0, 0, 0);

        // ===== act0 + L1(0) =====
        F b1a0, b1b0;
#pragma unroll
        for (int i = 0; i < 4; ++i)
            b1a0.u[i] = packh(__builtin_amdgcn_sinf(accA[2 * i]),
                              __builtin_amdgcn_sinf(accA[2 * i + 1]));
#pragma unroll
        for (int i = 0; i < 4; ++i)
            b1b0.u[i] = packh(__builtin_amdgcn_sinf(accA[8 + 2 * i]),
                              __builtin_amdgcn_sinf(accA[8 + 2 * i + 1]));
        f32x16 acc1A;
        acc1A = __builtin_amdgcn_mfma_f32_32x32x16_f16(a1[0], b1a0.v, zacc, 0, 0, 0);
        acc1A = __builtin_amdgcn_mfma_f32_32x32x16_f16(a1[1], b1b0.v, acc1A, 0, 0, 0);

        // ===== act1 + L1(1) =====
        F b1a1, b1b1;
#pragma unroll
        for (int i = 0; i < 4; ++i)
            b1a1.u[i] = packh(__builtin_amdgcn_sinf(accB[2 * i]),
                              __builtin_amdgcn_sinf(accB[2 * i + 1]));
#pragma unroll
        for (int i = 0; i < 4; ++i)
            b1b1.u[i] = packh(__builtin_amdgcn_sinf(accB[8 + 2 * i]),
                              __builtin_amdgcn_sinf(accB[8 + 2 * i + 1]));
        f32x16 acc1B;
        acc1B = __builtin_amdgcn_mfma_f32_32x32x16_f16(a1[0], b1a1.v, zacc, 0, 0, 0);
        acc1B = __builtin_amdgcn_mfma_f32_32x32x16_f16(a1[1], b1b1.v, acc1B, 0, 0, 0);

        // ===== act2 + merged dot-MFMA (d0 -> C row 0, d1 -> C row 4) =====
        F b2a0, b2b0, b2a1, b2b1;
#pragma unroll
        for (int i = 0; i < 4; ++i)
            b2a0.u[i] = packh(__builtin_amdgcn_sinf(acc1A[2 * i]),
                              __builtin_amdgcn_sinf(acc1A[2 * i + 1]));
#pragma unroll
        for (int i = 0; i < 4; ++i)
            b2b0.u[i] = packh(__builtin_amdgcn_sinf(acc1A[8 + 2 * i]),
                              __builtin_amdgcn_sinf(acc1A[8 + 2 * i + 1]));
#pragma unroll
        for (int i = 0; i < 4; ++i)
            b2a1.u[i] = packh(__builtin_amdgcn_sinf(acc1B[2 * i]),
                              __builtin_amdgcn_sinf(acc1B[2 * i + 1]));
#pragma unroll
        for (int i = 0; i < 4; ++i)
            b2b1.u[i] = packh(__builtin_amdgcn_sinf(acc1B[8 + 2 * i]),
                              __builtin_amdgcn_sinf(acc1B[8 + 2 * i + 1]));
        f32x16 accD;
        accD = __builtin_amdgcn_mfma_f32_32x32x16_f16(d0[0], b2a0.v, zacc, 0, 0, 0);
        accD = __builtin_amdgcn_mfma_f32_32x32x16_f16(d0[1], b2b0.v, accD, 0, 0, 0);
        accD = __builtin_amdgcn_mfma_f32_32x32x16_f16(d1[0], b2a1.v, accD, 0, 0, 0);
        accD = __builtin_amdgcn_mfma_f32_32x32x16_f16(d1[1], b2b1.v, accD, 0, 0, 0);

        // reg 0 of lane (h,q) = C[4h][q] = dot of point (h ? 32+q : q)
        out[p + 32 * h + q] = accD[0];

        xa = na;
        xb = nb;
    }
}

extern "C" void kernel_launch(void* const* d_in, const int* in_sizes, int n_in,
                              void* d_out, int out_size, void* d_ws, size_t ws_size,
                              hipStream_t stream) {
    const float* xf = (const float*)d_in[0];
    const float* W0 = (const float*)d_in[1];
    const float* W1 = (const float*)d_in[2];
    const float* W2 = (const float*)d_in[3];
    float* out = (float*)d_out;
    uint4* ws = (uint4*)d_ws;

    const int n = in_sizes[0] / 2;
    build_frags<<<1, 64, 0, stream>>>(W0, W1, W2, ws);

    const int nwaves = BLOCKS * 4;
    const int tiles = (n + 63) / 64;
    const int chunk = ((tiles + nwaves - 1) / nwaves) * 64;   // points per wave
    siren_mfma_kernel<<<BLOCKS, THREADS, 0, stream>>>(xf, ws, out, n, chunk);
}

// Round 19
// 26.907 us; speedup vs baseline: 1.3135x; 1.1423x over previous
//
#include <hip/hip_runtime.h>
#include <hip/hip_bf16.h>
#include <hip/hip_fp16.h>

// Siren fused, 32x32x16 fp16 MFMA, zero-LDS, triple sigma-cancellation.
// R19: SINGLE LAUNCH. The separate build_frags kernel serialized ~3-5us of
// launch+cold-load latency ahead of the main kernel in every graph replay
// (included in ALL R1-R18 timings). Fragments are now built in-register at
// wave start inside the persistent kernel (R18 structure: 1024 blocks,
// 8 tiles/wave): ~140 insts once per wave, amortized over 512 points.
// Weight reads are 128B-row coalesced; W0/W1/W2 total 10KB -> L1/L2 broadcast.

typedef _Float16 half8 __attribute__((ext_vector_type(8)));
typedef __fp16 fp16x2 __attribute__((ext_vector_type(2)));
typedef float f32x16 __attribute__((ext_vector_type(16)));

#define THREADS 256
#define BLOCKS 1024
#define INV2PI 0.15915494309189535f

__device__ __forceinline__ unsigned packh(float lo, float hi) {
    union { fp16x2 h; unsigned u; } v;
    v.h = __builtin_amdgcn_cvt_pkrtz(lo, hi);
    return v.u;
}

// enc chain: 12 sin + 12 cos of pi*2^j*xd via 2 seeds + 10 double-angle steps.
__device__ __forceinline__ void enc_chain(float xd, float sv[12], float cv[12]) {
    sv[0] = __builtin_amdgcn_sinf(xd * 0.5f);
    cv[0] = __builtin_amdgcn_cosf(xd * 0.5f);
#pragma unroll
    for (int j = 1; j < 6; ++j) {
        float t = sv[j - 1] + sv[j - 1];
        sv[j] = t * cv[j - 1];
        cv[j] = fmaf(-t, sv[j - 1], 1.0f);
    }
    sv[6] = __builtin_amdgcn_sinf(xd * 32.0f);
    cv[6] = __builtin_amdgcn_cosf(xd * 32.0f);
#pragma unroll
    for (int j = 7; j < 12; ++j) {
        float t = sv[j - 1] + sv[j - 1];
        sv[j] = t * cv[j - 1];
        cv[j] = fmaf(-t, sv[j - 1], 1.0f);
    }
}

__global__ __launch_bounds__(THREADS, 4) void siren_mfma_kernel(
    const float* __restrict__ xf,     // [N][2] flat
    const float* __restrict__ W0,     // [48][32]
    const float* __restrict__ W1,     // [32][32]
    const float* __restrict__ W2,     // [32]
    float* __restrict__ out,
    int n, int chunk)                 // chunk = points per wave (multiple of 64)
{
    const int lane = threadIdx.x & 63;
    const int wid = threadIdx.x >> 6;
    const int q = lane & 31, h = lane >> 5;
    const int wgid = blockIdx.x * 4 + wid;

    int p0 = wgid * chunk;
    if (p0 >= n) return;
    const int pend = min(p0 + chunk, n);

    const int c = q;   // weight column for this lane

    // ---- build fragments in-register, once per wave ----
    // A0 frags t=0..2: elem e = W0[h*24+8t+e][c]/2pi
    union F { unsigned u[4]; half8 v; };
    half8 a0[3], a1[2], d0[2], d1[2];
#pragma unroll
    for (int t = 0; t < 3; ++t) {
        F f;
#pragma unroll
        for (int i = 0; i < 4; ++i) {
            float lo = W0[(h * 24 + 8 * t + 2 * i) * 32 + c] * INV2PI;
            float hi = W0[(h * 24 + 8 * t + 2 * i + 1) * 32 + c] * INV2PI;
            f.u[i] = packh(lo, hi);
        }
        a0[t] = f.v;
    }
    // A1 frags t=0..1: elem e = W1[kap(h,t,e)][c]/2pi, kap = (e&3)+8*(e>>2)+4h+16t
#pragma unroll
    for (int t = 0; t < 2; ++t) {
        F f;
#pragma unroll
        for (int i = 0; i < 4; ++i) {
            int e0 = 2 * i, e1 = 2 * i + 1;
            int k0 = (e0 & 3) + 8 * (e0 >> 2) + 4 * h + 16 * t;
            int k1 = (e1 & 3) + 8 * (e1 >> 2) + 4 * h + 16 * t;
            f.u[i] = packh(W1[k0 * 32 + c] * INV2PI, W1[k1 * 32 + c] * INV2PI);
        }
        a1[t] = f.v;
    }
    // dot frags: W2 in row 0 (stream 0) / row 4 (stream 1)
#pragma unroll
    for (int s = 0; s < 2; ++s)
#pragma unroll
        for (int t = 0; t < 2; ++t) {
            F f;
#pragma unroll
            for (int i = 0; i < 4; ++i) {
                int e0 = 2 * i, e1 = 2 * i + 1;
                int k0 = (e0 & 3) + 8 * (e0 >> 2) + 4 * h + 16 * t;
                int k1 = (e1 & 3) + 8 * (e1 >> 2) + 4 * h + 16 * t;
                float lo = (c == 4 * s) ? W2[k0] : 0.0f;
                float hi = (c == 4 * s) ? W2[k1] : 0.0f;
                f.u[i] = packh(lo, hi);
            }
            if (s == 0) d0[t] = f.v; else d1[t] = f.v;
        }

    f32x16 zacc;
#pragma unroll
    for (int i = 0; i < 16; ++i) zacc[i] = 0.0f;

    // ---- first tile's x in flight ----
    float xa = xf[(p0 + q) * 2 + h];
    float xb = xf[(p0 + 32 + q) * 2 + h];

    for (int p = p0; p < pend; p += 64) {
        // prefetch next tile's x (hides under this tile's compute)
        const int pn = (p + 64 < pend) ? (p + 64) : p;
        float na = xf[(pn + q) * 2 + h];
        float nb = xf[(pn + 32 + q) * 2 + h];

        // ===== stream 0: enc + L0 =====
        F bf00, bf01, bf02;
        {
            float sv[12], cv[12];
            enc_chain(xa, sv, cv);
            bf00.u[0] = packh(sv[0], sv[1]);  bf00.u[1] = packh(sv[2], sv[3]);
            bf00.u[2] = packh(sv[4], sv[5]);  bf00.u[3] = packh(sv[6], sv[7]);
            bf01.u[0] = packh(sv[8], sv[9]);  bf01.u[1] = packh(sv[10], sv[11]);
            bf01.u[2] = packh(cv[0], cv[1]);  bf01.u[3] = packh(cv[2], cv[3]);
            bf02.u[0] = packh(cv[4], cv[5]);  bf02.u[1] = packh(cv[6], cv[7]);
            bf02.u[2] = packh(cv[8], cv[9]);  bf02.u[3] = packh(cv[10], cv[11]);
        }
        f32x16 accA;
        accA = __builtin_amdgcn_mfma_f32_32x32x16_f16(a0[0], bf00.v, zacc, 0, 0, 0);
        accA = __builtin_amdgcn_mfma_f32_32x32x16_f16(a0[1], bf01.v, accA, 0, 0, 0);
        accA = __builtin_amdgcn_mfma_f32_32x32x16_f16(a0[2], bf02.v, accA, 0, 0, 0);

        // ===== stream 1: enc + L0 =====
        F bf10, bf11, bf12;
        {
            float sv[12], cv[12];
            enc_chain(xb, sv, cv);
            bf10.u[0] = packh(sv[0], sv[1]);  bf10.u[1] = packh(sv[2], sv[3]);
            bf10.u[2] = packh(sv[4], sv[5]);  bf10.u[3] = packh(sv[6], sv[7]);
            bf11.u[0] = packh(sv[8], sv[9]);  bf11.u[1] = packh(sv[10], sv[11]);
            bf11.u[2] = packh(cv[0], cv[1]);  bf11.u[3] = packh(cv[2], cv[3]);
            bf12.u[0] = packh(cv[4], cv[5]);  bf12.u[1] = packh(cv[6], cv[7]);
            bf12.u[2] = packh(cv[8], cv[9]);  bf12.u[3] = packh(cv[10], cv[11]);
        }
        f32x16 accB;
        accB = __builtin_amdgcn_mfma_f32_32x32x16_f16(a0[0], bf10.v, zacc, 0, 0, 0);
        accB = __builtin_amdgcn_mfma_f32_32x32x16_f16(a0[1], bf11.v, accB, 0, 0, 0);
        accB = __builtin_amdgcn_mfma_f32_32x32x16_f16(a0[2], bf12.v, accB, 0, 0, 0);

        // ===== act0 + L1(0) =====
        F b1a0, b1b0;
#pragma unroll
        for (int i = 0; i < 4; ++i)
            b1a0.u[i] = packh(__builtin_amdgcn_sinf(accA[2 * i]),
                              __builtin_amdgcn_sinf(accA[2 * i + 1]));
#pragma unroll
        for (int i = 0; i < 4; ++i)
            b1b0.u[i] = packh(__builtin_amdgcn_sinf(accA[8 + 2 * i]),
                              __builtin_amdgcn_sinf(accA[8 + 2 * i + 1]));
        f32x16 acc1A;
        acc1A = __builtin_amdgcn_mfma_f32_32x32x16_f16(a1[0], b1a0.v, zacc, 0, 0, 0);
        acc1A = __builtin_amdgcn_mfma_f32_32x32x16_f16(a1[1], b1b0.v, acc1A, 0, 0, 0);

        // ===== act1 + L1(1) =====
        F b1a1, b1b1;
#pragma unroll
        for (int i = 0; i < 4; ++i)
            b1a1.u[i] = packh(__builtin_amdgcn_sinf(accB[2 * i]),
                              __builtin_amdgcn_sinf(accB[2 * i + 1]));
#pragma unroll
        for (int i = 0; i < 4; ++i)
            b1b1.u[i] = packh(__builtin_amdgcn_sinf(accB[8 + 2 * i]),
                              __builtin_amdgcn_sinf(accB[8 + 2 * i + 1]));
        f32x16 acc1B;
        acc1B = __builtin_amdgcn_mfma_f32_32x32x16_f16(a1[0], b1a1.v, zacc, 0, 0, 0);
        acc1B = __builtin_amdgcn_mfma_f32_32x32x16_f16(a1[1], b1b1.v, acc1B, 0, 0, 0);

        // ===== act2 + merged dot-MFMA (d0 -> C row 0, d1 -> C row 4) =====
        F b2a0, b2b0, b2a1, b2b1;
#pragma unroll
        for (int i = 0; i < 4; ++i)
            b2a0.u[i] = packh(__builtin_amdgcn_sinf(acc1A[2 * i]),
                              __builtin_amdgcn_sinf(acc1A[2 * i + 1]));
#pragma unroll
        for (int i = 0; i < 4; ++i)
            b2b0.u[i] = packh(__builtin_amdgcn_sinf(acc1A[8 + 2 * i]),
                              __builtin_amdgcn_sinf(acc1A[8 + 2 * i + 1]));
#pragma unroll
        for (int i = 0; i < 4; ++i)
            b2a1.u[i] = packh(__builtin_amdgcn_sinf(acc1B[2 * i]),
                              __builtin_amdgcn_sinf(acc1B[2 * i + 1]));
#pragma unroll
        for (int i = 0; i < 4; ++i)
            b2b1.u[i] = packh(__builtin_amdgcn_sinf(acc1B[8 + 2 * i]),
                              __builtin_amdgcn_sinf(acc1B[8 + 2 * i + 1]));
        f32x16 accD;
        accD = __builtin_amdgcn_mfma_f32_32x32x16_f16(d0[0], b2a0.v, zacc, 0, 0, 0);
        accD = __builtin_amdgcn_mfma_f32_32x32x16_f16(d0[1], b2b0.v, accD, 0, 0, 0);
        accD = __builtin_amdgcn_mfma_f32_32x32x16_f16(d1[0], b2a1.v, accD, 0, 0, 0);
        accD = __builtin_amdgcn_mfma_f32_32x32x16_f16(d1[1], b2b1.v, accD, 0, 0, 0);

        // reg 0 of lane (h,q) = C[4h][q] = dot of point (h ? 32+q : q)
        out[p + 32 * h + q] = accD[0];

        xa = na;
        xb = nb;
    }
}

extern "C" void kernel_launch(void* const* d_in, const int* in_sizes, int n_in,
                              void* d_out, int out_size, void* d_ws, size_t ws_size,
                              hipStream_t stream) {
    const float* xf = (const float*)d_in[0];
    const float* W0 = (const float*)d_in[1];
    const float* W1 = (const float*)d_in[2];
    const float* W2 = (const float*)d_in[3];
    float* out = (float*)d_out;

    const int n = in_sizes[0] / 2;
    const int nwaves = BLOCKS * 4;
    const int tiles = (n + 63) / 64;
    const int chunk = ((tiles + nwaves - 1) / nwaves) * 64;   // points per wave
    siren_mfma_kernel<<<BLOCKS, THREADS, 0, stream>>>(xf, W0, W1, W2, out, n, chunk);
}